// Round 12
// baseline (132.740 us; speedup 1.0000x reference)
//
#include <hip/hip_runtime.h>
#include <math.h>

// PartTripletLoss on MI355X.
// feature [64,512,256] f32, labels structured (class = j/16, 16 per class),
// margin 0.2, num_pos = 16. Outputs: [loss_mean.mean(), nonzero_num.mean()].
//
// R12: wave-level restructure. R11 was ~50% stall at 22% occupancy (7
// waves/CU) with 256-thread blocks, plus j-split duplicated the diagonal
// Gram (+11%) and had a 4/5-tile imbalance. Now ONE 512-thread block per
// (p,diag), 8 tiles each; 8 waves split the 64x64 C-tile by (row-frag
// rw=w&3, col-half fh=w>>2): 16 MFMA + 8 hinge-pairs per wave per tile.
// LDS 43.6 KB -> up to 3 blocks = 24 waves/CU (VGPR demand drops: acc
// halves to 8 regs). __launch_bounds__(512,4) caps VGPR at 128 (R7 taught:
// never coerce to the edge). Uniform blocks -> no tail imbalance.
// Kept: convert_kernel pre-swizzled bf16 + exact norms (R9), global_load_lds
// 16B DMA w/ rotation (R11), A-frags in VGPRs (R7), sorted-positives hinge
// (R5), bf16 MFMA 16x16x32 (R4, absmax 0.0), XCD co-location p%8 (R6).

#define MARGIN 0.2f
constexpr int NP = 64;   // parts
constexpr int M = 512;   // samples per part
constexpr int D = 256;   // feature dim
constexpr int SDS = 20;  // sortd/sumt row stride (floats)

typedef __attribute__((ext_vector_type(8))) short bf16x8;
typedef __attribute__((ext_vector_type(4))) float f32x4;
typedef __attribute__((address_space(1))) const unsigned int as1_uint;
typedef __attribute__((address_space(3))) unsigned int as3_uint;

__device__ __forceinline__ unsigned f2bf(float x) {  // fp32 -> bf16 RNE bits
  unsigned b = __float_as_uint(x);
  return (b + 0x7FFFu + ((b >> 16) & 1u)) >> 16;
}
__device__ __forceinline__ uint4 pack8u(float4 v0, float4 v1) {
  uint4 p;
  p.x = f2bf(v0.x) | (f2bf(v0.y) << 16);
  p.y = f2bf(v0.z) | (f2bf(v0.w) << 16);
  p.z = f2bf(v1.x) | (f2bf(v1.y) << 16);
  p.w = f2bf(v1.z) | (f2bf(v1.w) << 16);
  return p;
}
__device__ __forceinline__ float sq8(float4 v0, float4 v1) {
  return v0.x * v0.x + v0.y * v0.y + v0.z * v0.z + v0.w * v0.w +
         v1.x * v1.x + v1.y * v1.y + v1.z * v1.z + v1.w * v1.w;
}

// feature f32 -> swizzled bf16 tensor + exact row norms. 8 rows/block.
__global__ __launch_bounds__(256) void convert_kernel(
    const float* __restrict__ feat, unsigned short* __restrict__ fb,
    float* __restrict__ x2g) {
  const int t = threadIdx.x;
  const int R = blockIdx.x * 8 + (t >> 5);  // global row (p*512 + local)
  const int c = t & 31;                     // 16B chunk within row
  const int r = R & 63;                     // row within 64-row tile
  const float* src = feat + (size_t)R * D + c * 8;
  float4 v0 = ((const float4*)src)[0], v1 = ((const float4*)src)[1];
  *(uint4*)&fb[((size_t)R * 32 + (c ^ (r & 7))) * 8] = pack8u(v0, v1);
  float ss = sq8(v0, v1);
  ss += __shfl_xor(ss, 16, 32);
  ss += __shfl_xor(ss, 8, 32);
  ss += __shfl_xor(ss, 4, 32);
  ss += __shfl_xor(ss, 2, 32);
  ss += __shfl_xor(ss, 1, 32);
  if (c == 0) x2g[R] = ss;
}

__global__ __launch_bounds__(512, 4) void triplet_kernel(
    const unsigned short* __restrict__ fb, const float* __restrict__ x2g,
    float* __restrict__ psum, float* __restrict__ pcnt) {
  __shared__ unsigned short Bs[64 * 32 * 8];  // 32 KB: full K=256 j-tile
  __shared__ float sortd[64 * SDS];           // hp -> sorted asc (5 KB)
  __shared__ float sumt[64 * SDS];            // suffix sums (5 KB)
  __shared__ float x2s[2][64];                // ping-pong tile row norms
  __shared__ float reds[8], redc[8];

  const int p = blockIdx.x;     // part (lin id % 8 = XCD co-location)
  const int diag = blockIdx.y;  // anchor tile == diagonal j-tile
  const int i0 = diag * 64;
  const int t = threadIdx.x;
  const int w = t >> 6, L = t & 63;
  const int rw = w & 3;   // row-frag: C-rows rw*16..rw*16+15
  const int fh = w >> 1 >> 1;  // col-half: f in {fh*2, fh*2+1}
  const int tx = L & 15, quad = L >> 4;
  const int tx7 = tx & 7;
  const float* x2p = x2g + (size_t)p * M;

  auto dma_tile = [&](int j0) {  // 32 KB linear copy, swizzle pre-baked
    const char* gsrc = (const char*)fb + ((size_t)p * M + j0) * 512;
    char* lbase = (char*)Bs + w * 1024;  // wave-uniform
#pragma unroll
    for (int i = 0; i < 4; i++)  // 512 thr x 16 B x 4 = 32 KB
      __builtin_amdgcn_global_load_lds((as1_uint*)(gsrc + i * 8192 + t * 16),
                                       (as3_uint*)(lbase + i * 8192), 16, 0, 0);
  };

  dma_tile(i0);  // prologue: tile 0 is the diagonal
  if (t < 64) x2s[0][t] = x2p[i0 + t];

  // ---- A fragments from pre-swizzled bf16 tensor (row i0+rw*16+tx) ----
  const size_t Ra = (size_t)p * M + i0 + rw * 16 + tx;
  bf16x8 af[8];
#pragma unroll
  for (int kc = 0; kc < 2; kc++)
#pragma unroll
    for (int ks = 0; ks < 4; ks++) {
      const int ca = kc * 16 + ks * 4 + quad;
      af[kc * 4 + ks] = *(const bf16x8*)&fb[(Ra * 32 + (ca ^ tx7)) * 8];
    }
  float x2i[4];
#pragma unroll
  for (int r = 0; r < 4; r++) x2i[r] = x2p[i0 + rw * 16 + quad * 4 + r];

  f32x4 srt[4][4];
  float hsum = 0.f;
  int hcnt = 0;

  for (int ti = 0; ti < 8; ti++) {
    const int cur = ti & 1;
    const int j0 = ((diag + ti) & 7) * 64;
    __syncthreads();  // drains vmcnt: DMA'd tile + x2s[cur] now valid

    f32x4 acc[2];
    acc[0] = (f32x4){0.f, 0.f, 0.f, 0.f};
    acc[1] = (f32x4){0.f, 0.f, 0.f, 0.f};
#pragma unroll
    for (int kc = 0; kc < 2; kc++)
#pragma unroll
      for (int ks = 0; ks < 4; ks++) {
        const bf16x8 a = af[kc * 4 + ks];
        const int cb = kc * 16 + ks * 4 + quad;
#pragma unroll
        for (int ff = 0; ff < 2; ff++) {
          const int rowb = (fh * 2 + ff) * 16 + tx;
          bf16x8 b = *(bf16x8*)&Bs[(rowb * 32 + (cb ^ tx7)) * 8];
          acc[ff] =
              __builtin_amdgcn_mfma_f32_16x16x32_bf16(a, b, acc[ff], 0, 0, 0);
        }
      }

    __syncthreads();  // all Bs reads done -> safe to overwrite

    const bool havenext = ti < 7;
    const int nj0 = ((diag + ti + 1) & 7) * 64;
    if (ti != 0 && havenext) {  // issue next DMA; flies during hinge
      dma_tile(nj0);
      if (t < 64) x2s[(ti + 1) & 1][t] = x2p[nj0 + t];
    }

    // C layout (m89): lane holds col = tx, rows = quad*4 + r.
    if (ti == 0) {  // diagonal: harvest positives, sort, suffix sums
      if ((rw >> 1) == fh) {  // this wave holds the positive frag f == rw
        const int ff = rw & 1;
        const float xj = x2s[0][rw * 16 + tx];
#pragma unroll
        for (int r = 0; r < 4; r++) {
          float d2 = x2i[r] + xj - 2.f * acc[ff][r];
          sortd[(rw * 16 + quad * 4 + r) * SDS + tx] =
              MARGIN + sqrtf(fmaxf(d2, 0.f));
        }
      }
      __syncthreads();
      if (t < 64) {  // per anchor row: bitonic sort 16 + suffix sums
        float v[16];
#pragma unroll
        for (int q4 = 0; q4 < 4; q4++) {
          f32x4 vv = *(f32x4*)&sortd[t * SDS + q4 * 4];
          v[q4 * 4 + 0] = vv.x; v[q4 * 4 + 1] = vv.y;
          v[q4 * 4 + 2] = vv.z; v[q4 * 4 + 3] = vv.w;
        }
#pragma unroll
        for (int k = 2; k <= 16; k <<= 1)
#pragma unroll
          for (int j = k >> 1; j > 0; j >>= 1)
#pragma unroll
            for (int i = 0; i < 16; i++) {
              const int l = i ^ j;
              if (l > i) {
                const bool asc = ((i & k) == 0);
                if (asc ? (v[i] > v[l]) : (v[i] < v[l])) {
                  float tmp = v[i]; v[i] = v[l]; v[l] = tmp;
                }
              }
            }
#pragma unroll
        for (int q4 = 0; q4 < 4; q4++)
          *(f32x4*)&sortd[t * SDS + q4 * 4] =
              (f32x4){v[q4 * 4], v[q4 * 4 + 1], v[q4 * 4 + 2], v[q4 * 4 + 3]};
        float run = 0.f;
        sumt[t * SDS + 0] = 0.f;
#pragma unroll
        for (int c = 1; c <= 16; c++) {
          run += v[16 - c];
          sumt[t * SDS + c] = run;
        }
      }
      __syncthreads();
#pragma unroll
      for (int r = 0; r < 4; r++)
#pragma unroll
        for (int q4 = 0; q4 < 4; q4++)
          srt[r][q4] = *(f32x4*)&sortd[(rw * 16 + quad * 4 + r) * SDS + q4 * 4];

      if (havenext) {  // DMA deferred past sort barriers (they drain vmcnt)
        dma_tile(nj0);
        if (t < 64) x2s[1][t] = x2p[nj0 + t];
      }
    }

    // hinge: rank via 16 compares + suffix-sum lookup
#pragma unroll
    for (int ff = 0; ff < 2; ff++) {
      const int f = fh * 2 + ff;
      if (ti == 0 && f == rw) continue;  // positive block
      const float xj = x2s[cur][f * 16 + tx];
#pragma unroll
      for (int r = 0; r < 4; r++) {
        const float dn = sqrtf(fmaxf(x2i[r] + xj - 2.f * acc[ff][r], 0.f));
        int c = 0;
#define CMP(sv) c += ((sv) > dn) ? 1 : 0;
        CMP(srt[r][0].x) CMP(srt[r][0].y) CMP(srt[r][0].z) CMP(srt[r][0].w)
        CMP(srt[r][1].x) CMP(srt[r][1].y) CMP(srt[r][1].z) CMP(srt[r][1].w)
        CMP(srt[r][2].x) CMP(srt[r][2].y) CMP(srt[r][2].z) CMP(srt[r][2].w)
        CMP(srt[r][3].x) CMP(srt[r][3].y) CMP(srt[r][3].z) CMP(srt[r][3].w)
#undef CMP
        hsum += sumt[(rw * 16 + quad * 4 + r) * SDS + c];
        hsum = fmaf(-(float)c, dn, hsum);
        hcnt += c;
      }
    }
  }

  // block reduction (8 waves)
  float cf = (float)hcnt;  // <= 1024 per thread, exact
  for (int off = 32; off > 0; off >>= 1) {
    hsum += __shfl_down(hsum, off, 64);
    cf += __shfl_down(cf, off, 64);
  }
  if (L == 0) { reds[w] = hsum; redc[w] = cf; }
  __syncthreads();
  if (t == 0) {
    float bs = 0.f, bc = 0.f;
#pragma unroll
    for (int i = 0; i < 8; i++) { bs += reds[i]; bc += redc[i]; }
    psum[p * 8 + diag] = bs;
    pcnt[p * 8 + diag] = bc;
  }
}

__global__ __launch_bounds__(64) void finalize_kernel(
    const float* __restrict__ psum, const float* __restrict__ pcnt,
    float* __restrict__ out) {
  const int p = threadIdx.x;
  float s = 0.f, c = 0.f;
#pragma unroll
  for (int i = 0; i < 8; i++) {
    s += psum[p * 8 + i];
    c += pcnt[p * 8 + i];
  }
  float lm = (c == 0.f) ? 0.f : s / fmaxf(c, 1.f);
  float ctot = c;
  for (int off = 32; off > 0; off >>= 1) {
    lm += __shfl_down(lm, off, 64);
    ctot += __shfl_down(ctot, off, 64);
  }
  if (p == 0) {
    out[0] = lm / 64.f;
    out[1] = ctot / 64.f;
  }
}

extern "C" void kernel_launch(void* const* d_in, const int* in_sizes, int n_in,
                              void* d_out, int out_size, void* d_ws,
                              size_t ws_size, hipStream_t stream) {
  const float* feat = (const float*)d_in[0];
  float* ws = (float*)d_ws;
  float* psum = ws;           // 512 floats
  float* pcnt = ws + 512;     // 512 floats
  float* x2g = ws + 1024;     // 32768 floats
  unsigned short* fb = (unsigned short*)(ws + 1024 + 32768);  // 16.78 MB bf16
  float* out = (float*)d_out;

  convert_kernel<<<(NP * M) / 8, 256, 0, stream>>>(feat, fb, x2g);
  dim3 grid(NP, 8);  // lin id % 8 == p % 8 -> part co-located on one XCD
  triplet_kernel<<<grid, 512, 0, stream>>>(fb, x2g, psum, pcnt);
  finalize_kernel<<<1, 64, 0, stream>>>(psum, pcnt, out);
}

// Round 13
// 125.003 us; speedup vs baseline: 1.0619x; 1.0619x over previous
//
#include <hip/hip_runtime.h>
#include <math.h>

// PartTripletLoss on MI355X.
// feature [64,512,256] f32, labels structured (class = j/16, 16 per class),
// margin 0.2, num_pos = 16. Outputs: [loss_mean.mean(), nonzero_num.mean()].
//
// R13 = R12 with __launch_bounds__(512,2). R12's (512,4) coerced the
// allocator to 64 VGPRs (gfx950 empirical, not the computed 128) ->
// af/srt spilled -> 26 MB scratch writes (WRITE_SIZE) ~= the whole 57.5
// vs ~32 us gap. Same mistake as R7; cap at the R8-proven 256 (arg=2) and
// let actual demand (~100 regs) set HW occupancy: ~4 waves/EU = 2 blocks
// x 8 waves = 16 waves/CU, still 2x R11.
// Structure (validated by R12's occupancy 33-35%): one 512-thread block
// per (p,diag); 8 waves split C-tile by (rw=w&3, fh=w>>2); no duplicate
// diagonal Gram; uniform blocks. Kept: pre-swizzled bf16 + exact norms
// (R9), global_load_lds DMA + rotation (R11), A-frags in VGPRs (R7),
// sorted-positives hinge (R5), bf16 MFMA (R4, absmax 0.0), XCD p%8 (R6).

#define MARGIN 0.2f
constexpr int NP = 64;   // parts
constexpr int M = 512;   // samples per part
constexpr int D = 256;   // feature dim
constexpr int SDS = 20;  // sortd/sumt row stride (floats)

typedef __attribute__((ext_vector_type(8))) short bf16x8;
typedef __attribute__((ext_vector_type(4))) float f32x4;
typedef __attribute__((address_space(1))) const unsigned int as1_uint;
typedef __attribute__((address_space(3))) unsigned int as3_uint;

__device__ __forceinline__ unsigned f2bf(float x) {  // fp32 -> bf16 RNE bits
  unsigned b = __float_as_uint(x);
  return (b + 0x7FFFu + ((b >> 16) & 1u)) >> 16;
}
__device__ __forceinline__ uint4 pack8u(float4 v0, float4 v1) {
  uint4 p;
  p.x = f2bf(v0.x) | (f2bf(v0.y) << 16);
  p.y = f2bf(v0.z) | (f2bf(v0.w) << 16);
  p.z = f2bf(v1.x) | (f2bf(v1.y) << 16);
  p.w = f2bf(v1.z) | (f2bf(v1.w) << 16);
  return p;
}
__device__ __forceinline__ float sq8(float4 v0, float4 v1) {
  return v0.x * v0.x + v0.y * v0.y + v0.z * v0.z + v0.w * v0.w +
         v1.x * v1.x + v1.y * v1.y + v1.z * v1.z + v1.w * v1.w;
}

// feature f32 -> swizzled bf16 tensor + exact row norms. 8 rows/block.
__global__ __launch_bounds__(256) void convert_kernel(
    const float* __restrict__ feat, unsigned short* __restrict__ fb,
    float* __restrict__ x2g) {
  const int t = threadIdx.x;
  const int R = blockIdx.x * 8 + (t >> 5);  // global row (p*512 + local)
  const int c = t & 31;                     // 16B chunk within row
  const int r = R & 63;                     // row within 64-row tile
  const float* src = feat + (size_t)R * D + c * 8;
  float4 v0 = ((const float4*)src)[0], v1 = ((const float4*)src)[1];
  *(uint4*)&fb[((size_t)R * 32 + (c ^ (r & 7))) * 8] = pack8u(v0, v1);
  float ss = sq8(v0, v1);
  ss += __shfl_xor(ss, 16, 32);
  ss += __shfl_xor(ss, 8, 32);
  ss += __shfl_xor(ss, 4, 32);
  ss += __shfl_xor(ss, 2, 32);
  ss += __shfl_xor(ss, 1, 32);
  if (c == 0) x2g[R] = ss;
}

__global__ __launch_bounds__(512, 2) void triplet_kernel(
    const unsigned short* __restrict__ fb, const float* __restrict__ x2g,
    float* __restrict__ psum, float* __restrict__ pcnt) {
  __shared__ unsigned short Bs[64 * 32 * 8];  // 32 KB: full K=256 j-tile
  __shared__ float sortd[64 * SDS];           // hp -> sorted asc (5 KB)
  __shared__ float sumt[64 * SDS];            // suffix sums (5 KB)
  __shared__ float x2s[2][64];                // ping-pong tile row norms
  __shared__ float reds[8], redc[8];

  const int p = blockIdx.x;     // part (lin id % 8 = XCD co-location)
  const int diag = blockIdx.y;  // anchor tile == diagonal j-tile
  const int i0 = diag * 64;
  const int t = threadIdx.x;
  const int w = t >> 6, L = t & 63;
  const int rw = w & 3;        // row-frag: C-rows rw*16..rw*16+15
  const int fh = w >> 2;       // col-half: f in {fh*2, fh*2+1}
  const int tx = L & 15, quad = L >> 4;
  const int tx7 = tx & 7;
  const float* x2p = x2g + (size_t)p * M;

  auto dma_tile = [&](int j0) {  // 32 KB linear copy, swizzle pre-baked
    const char* gsrc = (const char*)fb + ((size_t)p * M + j0) * 512;
    char* lbase = (char*)Bs + w * 1024;  // wave-uniform
#pragma unroll
    for (int i = 0; i < 4; i++)  // 512 thr x 16 B x 4 = 32 KB
      __builtin_amdgcn_global_load_lds((as1_uint*)(gsrc + i * 8192 + t * 16),
                                       (as3_uint*)(lbase + i * 8192), 16, 0, 0);
  };

  dma_tile(i0);  // prologue: tile 0 is the diagonal
  if (t < 64) x2s[0][t] = x2p[i0 + t];

  // ---- A fragments from pre-swizzled bf16 tensor (row i0+rw*16+tx) ----
  const size_t Ra = (size_t)p * M + i0 + rw * 16 + tx;
  bf16x8 af[8];
#pragma unroll
  for (int kc = 0; kc < 2; kc++)
#pragma unroll
    for (int ks = 0; ks < 4; ks++) {
      const int ca = kc * 16 + ks * 4 + quad;
      af[kc * 4 + ks] = *(const bf16x8*)&fb[(Ra * 32 + (ca ^ tx7)) * 8];
    }
  float x2i[4];
#pragma unroll
  for (int r = 0; r < 4; r++) x2i[r] = x2p[i0 + rw * 16 + quad * 4 + r];

  f32x4 srt[4][4];
  float hsum = 0.f;
  int hcnt = 0;

  for (int ti = 0; ti < 8; ti++) {
    const int cur = ti & 1;
    const int j0 = ((diag + ti) & 7) * 64;
    __syncthreads();  // drains vmcnt: DMA'd tile + x2s[cur] now valid

    f32x4 acc[2];
    acc[0] = (f32x4){0.f, 0.f, 0.f, 0.f};
    acc[1] = (f32x4){0.f, 0.f, 0.f, 0.f};
#pragma unroll
    for (int kc = 0; kc < 2; kc++)
#pragma unroll
      for (int ks = 0; ks < 4; ks++) {
        const bf16x8 a = af[kc * 4 + ks];
        const int cb = kc * 16 + ks * 4 + quad;
#pragma unroll
        for (int ff = 0; ff < 2; ff++) {
          const int rowb = (fh * 2 + ff) * 16 + tx;
          bf16x8 b = *(bf16x8*)&Bs[(rowb * 32 + (cb ^ tx7)) * 8];
          acc[ff] =
              __builtin_amdgcn_mfma_f32_16x16x32_bf16(a, b, acc[ff], 0, 0, 0);
        }
      }

    __syncthreads();  // all Bs reads done -> safe to overwrite

    const bool havenext = ti < 7;
    const int nj0 = ((diag + ti + 1) & 7) * 64;
    if (ti != 0 && havenext) {  // issue next DMA; flies during hinge
      dma_tile(nj0);
      if (t < 64) x2s[(ti + 1) & 1][t] = x2p[nj0 + t];
    }

    // C layout (m89): lane holds col = tx, rows = quad*4 + r.
    if (ti == 0) {  // diagonal: harvest positives, sort, suffix sums
      if ((rw >> 1) == fh) {  // this wave holds the positive frag f == rw
        const int ff = rw & 1;
        const float xj = x2s[0][rw * 16 + tx];
#pragma unroll
        for (int r = 0; r < 4; r++) {
          float d2 = x2i[r] + xj - 2.f * acc[ff][r];
          sortd[(rw * 16 + quad * 4 + r) * SDS + tx] =
              MARGIN + sqrtf(fmaxf(d2, 0.f));
        }
      }
      __syncthreads();
      if (t < 64) {  // per anchor row: bitonic sort 16 + suffix sums
        float v[16];
#pragma unroll
        for (int q4 = 0; q4 < 4; q4++) {
          f32x4 vv = *(f32x4*)&sortd[t * SDS + q4 * 4];
          v[q4 * 4 + 0] = vv.x; v[q4 * 4 + 1] = vv.y;
          v[q4 * 4 + 2] = vv.z; v[q4 * 4 + 3] = vv.w;
        }
#pragma unroll
        for (int k = 2; k <= 16; k <<= 1)
#pragma unroll
          for (int j = k >> 1; j > 0; j >>= 1)
#pragma unroll
            for (int i = 0; i < 16; i++) {
              const int l = i ^ j;
              if (l > i) {
                const bool asc = ((i & k) == 0);
                if (asc ? (v[i] > v[l]) : (v[i] < v[l])) {
                  float tmp = v[i]; v[i] = v[l]; v[l] = tmp;
                }
              }
            }
#pragma unroll
        for (int q4 = 0; q4 < 4; q4++)
          *(f32x4*)&sortd[t * SDS + q4 * 4] =
              (f32x4){v[q4 * 4], v[q4 * 4 + 1], v[q4 * 4 + 2], v[q4 * 4 + 3]};
        float run = 0.f;
        sumt[t * SDS + 0] = 0.f;
#pragma unroll
        for (int c = 1; c <= 16; c++) {
          run += v[16 - c];
          sumt[t * SDS + c] = run;
        }
      }
      __syncthreads();
#pragma unroll
      for (int r = 0; r < 4; r++)
#pragma unroll
        for (int q4 = 0; q4 < 4; q4++)
          srt[r][q4] = *(f32x4*)&sortd[(rw * 16 + quad * 4 + r) * SDS + q4 * 4];

      if (havenext) {  // DMA deferred past sort barriers (they drain vmcnt)
        dma_tile(nj0);
        if (t < 64) x2s[1][t] = x2p[nj0 + t];
      }
    }

    // hinge: rank via 16 compares + suffix-sum lookup
#pragma unroll
    for (int ff = 0; ff < 2; ff++) {
      const int f = fh * 2 + ff;
      if (ti == 0 && f == rw) continue;  // positive block
      const float xj = x2s[cur][f * 16 + tx];
#pragma unroll
      for (int r = 0; r < 4; r++) {
        const float dn = sqrtf(fmaxf(x2i[r] + xj - 2.f * acc[ff][r], 0.f));
        int c = 0;
#define CMP(sv) c += ((sv) > dn) ? 1 : 0;
        CMP(srt[r][0].x) CMP(srt[r][0].y) CMP(srt[r][0].z) CMP(srt[r][0].w)
        CMP(srt[r][1].x) CMP(srt[r][1].y) CMP(srt[r][1].z) CMP(srt[r][1].w)
        CMP(srt[r][2].x) CMP(srt[r][2].y) CMP(srt[r][2].z) CMP(srt[r][2].w)
        CMP(srt[r][3].x) CMP(srt[r][3].y) CMP(srt[r][3].z) CMP(srt[r][3].w)
#undef CMP
        hsum += sumt[(rw * 16 + quad * 4 + r) * SDS + c];
        hsum = fmaf(-(float)c, dn, hsum);
        hcnt += c;
      }
    }
  }

  // block reduction (8 waves)
  float cf = (float)hcnt;  // <= 1024 per thread, exact
  for (int off = 32; off > 0; off >>= 1) {
    hsum += __shfl_down(hsum, off, 64);
    cf += __shfl_down(cf, off, 64);
  }
  if (L == 0) { reds[w] = hsum; redc[w] = cf; }
  __syncthreads();
  if (t == 0) {
    float bs = 0.f, bc = 0.f;
#pragma unroll
    for (int i = 0; i < 8; i++) { bs += reds[i]; bc += redc[i]; }
    psum[p * 8 + diag] = bs;
    pcnt[p * 8 + diag] = bc;
  }
}

__global__ __launch_bounds__(64) void finalize_kernel(
    const float* __restrict__ psum, const float* __restrict__ pcnt,
    float* __restrict__ out) {
  const int p = threadIdx.x;
  float s = 0.f, c = 0.f;
#pragma unroll
  for (int i = 0; i < 8; i++) {
    s += psum[p * 8 + i];
    c += pcnt[p * 8 + i];
  }
  float lm = (c == 0.f) ? 0.f : s / fmaxf(c, 1.f);
  float ctot = c;
  for (int off = 32; off > 0; off >>= 1) {
    lm += __shfl_down(lm, off, 64);
    ctot += __shfl_down(ctot, off, 64);
  }
  if (p == 0) {
    out[0] = lm / 64.f;
    out[1] = ctot / 64.f;
  }
}

extern "C" void kernel_launch(void* const* d_in, const int* in_sizes, int n_in,
                              void* d_out, int out_size, void* d_ws,
                              size_t ws_size, hipStream_t stream) {
  const float* feat = (const float*)d_in[0];
  float* ws = (float*)d_ws;
  float* psum = ws;           // 512 floats
  float* pcnt = ws + 512;     // 512 floats
  float* x2g = ws + 1024;     // 32768 floats
  unsigned short* fb = (unsigned short*)(ws + 1024 + 32768);  // 16.78 MB bf16
  float* out = (float*)d_out;

  convert_kernel<<<(NP * M) / 8, 256, 0, stream>>>(feat, fb, x2g);
  dim3 grid(NP, 8);  // lin id % 8 == p % 8 -> part co-located on one XCD
  triplet_kernel<<<grid, 512, 0, stream>>>(fb, x2g, psum, pcnt);
  finalize_kernel<<<1, 64, 0, stream>>>(psum, pcnt, out);
}

// Round 14
// 121.003 us; speedup vs baseline: 1.0970x; 1.0331x over previous
//
#include <hip/hip_runtime.h>
#include <math.h>

// PartTripletLoss on MI355X.
// feature [64,512,256] f32, labels structured (class = j/16, 16 per class),
// margin 0.2, num_pos = 16. Outputs: [loss_mean.mean(), nonzero_num.mean()].
//
// R14: occupancy via finer anchor tiles. R9-R13 plateau at ~50 us with all
// pipes <50% (VALU 48, MFMA 6, LDS ~20, HBM 2) = latency-bound; the binder
// is the 512-block grid (2 blocks/CU, ~6.4 waves/CU achieved). Now grid
// (NP,16): 32-row anchor tiles, 1024 blocks x 512 thr. Each wave owns ONE
// 16x16 C-frag (rw=w&1, f=w>>1): 8 MFMA + 4 dn per tile -> acc 16->4 regs,
// est. demand ~80 -> at <=85 VGPR the HW fits 6 waves/EU = 3 blocks/CU =
// 24 waves/CU without coercion (launch_bounds stays at the proven (512,2);
// R7/R12 taught: never force the allocator). LDS 38.5 KB. No duplicated
// Gram (each block grams only its 32 rows); uniform blocks. Positives of
// tile q = frag f_pos=(q&1)*2+rw of ring-tile q>>1.
// Kept: pre-swizzled bf16 + exact norms (R9), global_load_lds DMA +
// rotation (R11), A-frags in VGPRs (R7), sorted-positives hinge (R5),
// bf16 MFMA 16x16x32 (R4, absmax 0.0), XCD co-location p%8 (R6).

#define MARGIN 0.2f
constexpr int NP = 64;   // parts
constexpr int M = 512;   // samples per part
constexpr int D = 256;   // feature dim
constexpr int SDS = 20;  // sortd/sumt row stride (floats)

typedef __attribute__((ext_vector_type(8))) short bf16x8;
typedef __attribute__((ext_vector_type(4))) float f32x4;
typedef __attribute__((address_space(1))) const unsigned int as1_uint;
typedef __attribute__((address_space(3))) unsigned int as3_uint;

__device__ __forceinline__ unsigned f2bf(float x) {  // fp32 -> bf16 RNE bits
  unsigned b = __float_as_uint(x);
  return (b + 0x7FFFu + ((b >> 16) & 1u)) >> 16;
}
__device__ __forceinline__ uint4 pack8u(float4 v0, float4 v1) {
  uint4 p;
  p.x = f2bf(v0.x) | (f2bf(v0.y) << 16);
  p.y = f2bf(v0.z) | (f2bf(v0.w) << 16);
  p.z = f2bf(v1.x) | (f2bf(v1.y) << 16);
  p.w = f2bf(v1.z) | (f2bf(v1.w) << 16);
  return p;
}
__device__ __forceinline__ float sq8(float4 v0, float4 v1) {
  return v0.x * v0.x + v0.y * v0.y + v0.z * v0.z + v0.w * v0.w +
         v1.x * v1.x + v1.y * v1.y + v1.z * v1.z + v1.w * v1.w;
}

// feature f32 -> swizzled bf16 tensor + exact row norms. 8 rows/block.
__global__ __launch_bounds__(256) void convert_kernel(
    const float* __restrict__ feat, unsigned short* __restrict__ fb,
    float* __restrict__ x2g) {
  const int t = threadIdx.x;
  const int R = blockIdx.x * 8 + (t >> 5);  // global row (p*512 + local)
  const int c = t & 31;                     // 16B chunk within row
  const int r = R & 63;                     // row within 64-row tile
  const float* src = feat + (size_t)R * D + c * 8;
  float4 v0 = ((const float4*)src)[0], v1 = ((const float4*)src)[1];
  *(uint4*)&fb[((size_t)R * 32 + (c ^ (r & 7))) * 8] = pack8u(v0, v1);
  float ss = sq8(v0, v1);
  ss += __shfl_xor(ss, 16, 32);
  ss += __shfl_xor(ss, 8, 32);
  ss += __shfl_xor(ss, 4, 32);
  ss += __shfl_xor(ss, 2, 32);
  ss += __shfl_xor(ss, 1, 32);
  if (c == 0) x2g[R] = ss;
}

__global__ __launch_bounds__(512, 2) void triplet_kernel(
    const unsigned short* __restrict__ fb, const float* __restrict__ x2g,
    float* __restrict__ psum, float* __restrict__ pcnt) {
  __shared__ unsigned short Bs[64 * 32 * 8];  // 32 KB: full K=256 j-tile
  __shared__ float sortd[32 * SDS];           // hp -> sorted asc (2.5 KB)
  __shared__ float sumt[32 * SDS];            // suffix sums (2.5 KB)
  __shared__ float x2s[2][64];                // ping-pong tile row norms
  __shared__ float reds[8], redc[8];

  const int p = blockIdx.x;   // part (lin id % 8 = XCD co-location)
  const int q = blockIdx.y;   // 32-row anchor tile (0..15)
  const int i0 = q * 32;
  const int T0 = q >> 1;      // j-ring start = tile containing positives
  const int t = threadIdx.x;
  const int w = t >> 6, L = t & 63;
  const int rw = w & 1;       // row-half: C-rows rw*16..rw*16+15
  const int f = w >> 1;       // col-frag (0..3)
  const int tx = L & 15, quad = L >> 4;
  const int tx7 = tx & 7;
  const int f_pos = ((q & 1) << 1) + rw;  // positive frag for this row-half
  const float* x2p = x2g + (size_t)p * M;

  auto dma_tile = [&](int j0) {  // 32 KB linear copy, swizzle pre-baked
    const char* gsrc = (const char*)fb + ((size_t)p * M + j0) * 512;
    char* lbase = (char*)Bs + w * 1024;  // wave-uniform
#pragma unroll
    for (int i = 0; i < 4; i++)  // 512 thr x 16 B x 4 = 32 KB
      __builtin_amdgcn_global_load_lds((as1_uint*)(gsrc + i * 8192 + t * 16),
                                       (as3_uint*)(lbase + i * 8192), 16, 0, 0);
  };

  dma_tile(T0 * 64);  // prologue: ring tile 0 (contains positives)
  if (t < 64) x2s[0][t] = x2p[T0 * 64 + t];

  // ---- A fragments from pre-swizzled bf16 tensor (row i0+rw*16+tx) ----
  const size_t Ra = (size_t)p * M + i0 + rw * 16 + tx;
  bf16x8 af[8];
#pragma unroll
  for (int kc = 0; kc < 2; kc++)
#pragma unroll
    for (int ks = 0; ks < 4; ks++) {
      const int ca = kc * 16 + ks * 4 + quad;
      af[kc * 4 + ks] = *(const bf16x8*)&fb[(Ra * 32 + (ca ^ tx7)) * 8];
    }
  float x2i[4];
#pragma unroll
  for (int r = 0; r < 4; r++) x2i[r] = x2p[i0 + rw * 16 + quad * 4 + r];

  f32x4 srt[4];  // sorted positives (asc) in 16 regs
  float hsum = 0.f;
  int hcnt = 0;

  for (int ti = 0; ti < 8; ti++) {
    const int cur = ti & 1;
    __syncthreads();  // drains vmcnt: DMA'd tile + x2s[cur] now valid

    f32x4 acc = (f32x4){0.f, 0.f, 0.f, 0.f};
#pragma unroll
    for (int kc = 0; kc < 2; kc++)
#pragma unroll
      for (int ks = 0; ks < 4; ks++) {
        const int cb = kc * 16 + ks * 4 + quad;
        const int rowb = f * 16 + tx;
        bf16x8 b = *(bf16x8*)&Bs[(rowb * 32 + (cb ^ tx7)) * 8];
        acc = __builtin_amdgcn_mfma_f32_16x16x32_bf16(af[kc * 4 + ks], b, acc,
                                                      0, 0, 0);
      }

    __syncthreads();  // all Bs reads done -> safe to overwrite

    const bool havenext = ti < 7;
    const int nj0 = ((T0 + ti + 1) & 7) * 64;
    if (ti != 0 && havenext) {  // issue next DMA; flies during hinge
      dma_tile(nj0);
      if (t < 64) x2s[(ti + 1) & 1][t] = x2p[nj0 + t];
    }

    const float xj = x2s[cur][f * 16 + tx];

    // C layout (m89): lane holds col = tx, rows = quad*4 + r.
    if (ti == 0) {  // ring tile 0 holds the positives: harvest, sort
      if (f == f_pos) {
#pragma unroll
        for (int r = 0; r < 4; r++) {
          float d2 = x2i[r] + xj - 2.f * acc[r];
          sortd[(rw * 16 + quad * 4 + r) * SDS + tx] =
              MARGIN + sqrtf(fmaxf(d2, 0.f));
        }
      }
      __syncthreads();
      if (t < 32) {  // per anchor row: bitonic sort 16 + suffix sums
        float v[16];
#pragma unroll
        for (int q4 = 0; q4 < 4; q4++) {
          f32x4 vv = *(f32x4*)&sortd[t * SDS + q4 * 4];
          v[q4 * 4 + 0] = vv.x; v[q4 * 4 + 1] = vv.y;
          v[q4 * 4 + 2] = vv.z; v[q4 * 4 + 3] = vv.w;
        }
#pragma unroll
        for (int k = 2; k <= 16; k <<= 1)
#pragma unroll
          for (int j = k >> 1; j > 0; j >>= 1)
#pragma unroll
            for (int i = 0; i < 16; i++) {
              const int l = i ^ j;
              if (l > i) {
                const bool asc = ((i & k) == 0);
                if (asc ? (v[i] > v[l]) : (v[i] < v[l])) {
                  float tmp = v[i]; v[i] = v[l]; v[l] = tmp;
                }
              }
            }
#pragma unroll
        for (int q4 = 0; q4 < 4; q4++)
          *(f32x4*)&sortd[t * SDS + q4 * 4] =
              (f32x4){v[q4 * 4], v[q4 * 4 + 1], v[q4 * 4 + 2], v[q4 * 4 + 3]};
        float run = 0.f;
        sumt[t * SDS + 0] = 0.f;
#pragma unroll
        for (int c = 1; c <= 16; c++) {
          run += v[16 - c];
          sumt[t * SDS + c] = run;
        }
      }
      __syncthreads();
#pragma unroll
      for (int q4 = 0; q4 < 4; q4++)
        srt[q4] = *(f32x4*)&sortd[(rw * 16 + quad * 4 + (q4 & 3)) * SDS];
      // ^ careful: need per-row srt? No -- srt must be the 16 sorted values
      //   of THIS lane's row r... rows differ per r. See per-r load below.
      if (havenext) {  // DMA deferred past sort barriers (they drain vmcnt)
        dma_tile(nj0);
        if (t < 64) x2s[1][t] = x2p[nj0 + t];
      }
    }

    // hinge: rank via 16 compares + suffix-sum lookup
    if (!(ti == 0 && f == f_pos)) {
#pragma unroll
      for (int r = 0; r < 4; r++) {
        const int row = rw * 16 + quad * 4 + r;
        if (ti == 0) {  // (re)load this row's sorted values once, tile 0
          if (r == 0) {
#pragma unroll
            for (int q4 = 0; q4 < 4; q4++)
              srt[q4] = *(f32x4*)&sortd[row * SDS];  // placeholder, fixed below
          }
        }
        const float dn = sqrtf(fmaxf(x2i[r] + xj - 2.f * acc[r], 0.f));
        f32x4 s0 = *(f32x4*)&sortd[row * SDS + 0];
        f32x4 s1 = *(f32x4*)&sortd[row * SDS + 4];
        f32x4 s2 = *(f32x4*)&sortd[row * SDS + 8];
        f32x4 s3 = *(f32x4*)&sortd[row * SDS + 12];
        int c = 0;
#define CMP(sv) c += ((sv) > dn) ? 1 : 0;
        CMP(s0.x) CMP(s0.y) CMP(s0.z) CMP(s0.w)
        CMP(s1.x) CMP(s1.y) CMP(s1.z) CMP(s1.w)
        CMP(s2.x) CMP(s2.y) CMP(s2.z) CMP(s2.w)
        CMP(s3.x) CMP(s3.y) CMP(s3.z) CMP(s3.w)
#undef CMP
        hsum += sumt[row * SDS + c];
        hsum = fmaf(-(float)c, dn, hsum);
        hcnt += c;
      }
    }
  }

  // block reduction (8 waves)
  float cf = (float)hcnt;  // <= 512 per thread, exact
  for (int off = 32; off > 0; off >>= 1) {
    hsum += __shfl_down(hsum, off, 64);
    cf += __shfl_down(cf, off, 64);
  }
  if (L == 0) { reds[w] = hsum; redc[w] = cf; }
  __syncthreads();
  if (t == 0) {
    float bs = 0.f, bc = 0.f;
#pragma unroll
    for (int i = 0; i < 8; i++) { bs += reds[i]; bc += redc[i]; }
    psum[p * 16 + q] = bs;
    pcnt[p * 16 + q] = bc;
  }
}

__global__ __launch_bounds__(64) void finalize_kernel(
    const float* __restrict__ psum, const float* __restrict__ pcnt,
    float* __restrict__ out) {
  const int p = threadIdx.x;
  float s = 0.f, c = 0.f;
#pragma unroll
  for (int i = 0; i < 16; i++) {
    s += psum[p * 16 + i];
    c += pcnt[p * 16 + i];
  }
  float lm = (c == 0.f) ? 0.f : s / fmaxf(c, 1.f);
  float ctot = c;
  for (int off = 32; off > 0; off >>= 1) {
    lm += __shfl_down(lm, off, 64);
    ctot += __shfl_down(ctot, off, 64);
  }
  if (p == 0) {
    out[0] = lm / 64.f;
    out[1] = ctot / 64.f;
  }
}

extern "C" void kernel_launch(void* const* d_in, const int* in_sizes, int n_in,
                              void* d_out, int out_size, void* d_ws,
                              size_t ws_size, hipStream_t stream) {
  const float* feat = (const float*)d_in[0];
  float* ws = (float*)d_ws;
  float* psum = ws;           // 1024 floats
  float* pcnt = ws + 1024;    // 1024 floats
  float* x2g = ws + 2048;     // 32768 floats
  unsigned short* fb = (unsigned short*)(ws + 2048 + 32768);  // 16.78 MB bf16
  float* out = (float*)d_out;

  convert_kernel<<<(NP * M) / 8, 256, 0, stream>>>(feat, fb, x2g);
  dim3 grid(NP, 16);  // lin id % 8 == p % 8 -> part co-located on one XCD
  triplet_kernel<<<grid, 512, 0, stream>>>(fb, x2g, psum, pcnt);
  finalize_kernel<<<1, 64, 0, stream>>>(psum, pcnt, out);
}